// Round 9
// baseline (938.660 us; speedup 1.0000x reference)
//
#include <hip/hip_runtime.h>
#include <hip/hip_fp16.h>
#include <utility>
#include <type_traits>

// =====================================================================
// 16-qubit, batch-256 statevector simulator.  R9 architecture:
//
//  * one workgroup (512 threads) per batch element; 128 amps/thread,
//    SPLIT: 64 in registers (h=0) + 64 in a 128 KB LDS array (h=1).
//  * Allocator model (R2-R8 counters): VGPR budget = thread-count-only
//    heuristic -> 512 thr = 128 regs, 1024 thr = 64 regs; attributes
//    ignored.  R8 (1024 thr, 32/32 split) starved ILP at 64 regs
//    (VALUBusy 27%).  At 512 thr the 64/64 split leaves ~50 free regs
//    for concurrent LDS RMW chains -> no spill AND latency overlap.
//  * CNOT rings virtualized into GF(2) storage maps; gates are pair
//    updates j <-> j^m with role parity(c&j) (R8-validated protocol).
//  * physical j = [r:6][h:1][lane:6][wave:3].  Gate taxonomy:
//      - m thread-local        -> reg pairs + own-slice LDS pairs
//      - m has h               -> reg <-> partner-LDS direct (any mt,
//                                 incl. wave-crossing; no staging)
//      - m lane-only, no h     -> shfl (regs) + LDS owner-protocol
//      - m wave-crossing, no h -> BAD: staged exchange (regs) + owner
//    constexpr greedy picks h + 3 wave bits to minimize BAD gates.
//  * one __syncthreads per cross-thread gate; LDS layout row*512+tid
//    (stride-1, 0 bank conflicts measured in R8).
// =====================================================================

// ---------------- compile-time GF(2) matrices ----------------
struct M16 { unsigned r[16]; };

constexpr M16 ident() { M16 m{}; for (int i = 0; i < 16; ++i) m.r[i] = 1u << i; return m; }

constexpr M16 ringm(int s) {
  M16 m = ident();
  for (int i = 15; i >= 0; --i) {
    int pc = 15 - i;
    int pt = 15 - ((i + s) & 15);
    m.r[pt] ^= m.r[pc];
  }
  return m;
}

constexpr M16 mmul(M16 A, M16 B) {
  M16 C{};
  for (int p = 0; p < 16; ++p) {
    unsigned v = 0;
    for (int q = 0; q < 16; ++q) if ((A.r[p] >> q) & 1u) v ^= B.r[q];
    C.r[p] = v;
  }
  return C;
}

constexpr M16 minv(M16 A) {
  M16 I = ident();
  for (int col = 0; col < 16; ++col) {
    int piv = -1;
    for (int row = col; row < 16; ++row) if ((A.r[row] >> col) & 1u) { piv = row; break; }
    unsigned t = A.r[piv]; A.r[piv] = A.r[col]; A.r[col] = t;
    t = I.r[piv]; I.r[piv] = I.r[col]; I.r[col] = t;
    for (int row = 0; row < 16; ++row)
      if (row != col && ((A.r[row] >> col) & 1u)) { A.r[row] ^= A.r[col]; I.r[row] ^= I.r[col]; }
  }
  return I;
}

constexpr bool meq(M16 a, M16 b) { for (int i = 0; i < 16; ++i) if (a.r[i] != b.r[i]) return false; return true; }
constexpr unsigned colmask(M16 P, int b) { unsigned m = 0; for (int p = 0; p < 16; ++p) m |= ((P.r[p] >> b) & 1u) << p; return m; }
constexpr int popc16(unsigned x) { int c = 0; for (int i = 0; i < 16; ++i) c += (x >> i) & 1; return c; }
constexpr int topbit_pow(unsigned x) { int b = 0; for (int i = 0; i < 16; ++i) if ((x >> i) & 1) b = i; return 1 << b; }
constexpr int ctzu(unsigned x) { for (int i = 0; i < 32; ++i) if ((x >> i) & 1) return i; return 32; }

struct Tables { unsigned gm[64]; unsigned gc[64]; unsigned meas[16]; };

constexpr Tables make_tables() {
  Tables T{};
  M16 R1 = ringm(1), R2 = ringm(2);
  M16 P0 = R1;
  M16 P1 = mmul(R1, R1);
  M16 P2 = mmul(P1, R2);
  M16 P3 = mmul(P2, R2);
  M16 P[4] = { P0, P1, P2, P3 };
  for (int k = 0; k < 4; ++k) {
    M16 A = minv(P[k]);
    for (int b = 0; b < 16; ++b) {
      T.gm[k * 16 + b] = colmask(P[k], b);
      T.gc[k * 16 + b] = A.r[b];
    }
  }
  M16 A5 = minv(P[3]);
  for (int w = 0; w < 16; ++w) T.meas[w] = A5.r[15 - w];
  return T;
}

constexpr Tables TB = make_tables();

constexpr bool check_tables() {
  for (int g = 0; g < 64; ++g) if ((popc16(TB.gm[g] & TB.gc[g]) & 1) != 1) return false;
  if (!meq(mmul(ringm(1), minv(ringm(1))), ident())) return false;
  if (!meq(mmul(ringm(2), minv(ringm(2))), ident())) return false;
  return true;
}
static_assert(check_tables(), "GF(2) table inconsistency");
static_assert(sizeof(__half2) == 4, "half2 size");

// ---------------- bit-role assignment (constexpr greedy) ----------------
// h position + 3 wave positions minimizing BAD gates (wave-crossing
// without h); then 6 r positions (of remaining 12) maximizing
// thread-local gates.  phys layout: r=0..5, h=6, lane=7..12, wave=13..15.
struct Assign {
  int hpos; unsigned wset, rset, lset;
  int phys_of[16];
  int orig_of[16];
  unsigned pm[64], pc[64], pmeas[16];
};

constexpr Assign make_assign() {
  Assign A{};
  int bestBad = 1000, bh = -1; unsigned bw = 0;
  for (int h = 0; h < 16; ++h) {
    bool alive[64];
    for (int g = 0; g < 64; ++g) alive[g] = ((TB.gm[g] >> h) & 1u) == 0u;
    unsigned w = 0;
    int covered = 0;
    for (int pick = 0; pick < 3; ++pick) {
      int bestP = -1, bestC = 1000000;
      for (int p = 0; p < 16; ++p) {
        if (p == h || ((w >> p) & 1u)) continue;
        int cnt = 0;
        for (int g = 0; g < 64; ++g)
          if (alive[g] && ((TB.gm[g] >> p) & 1u)) ++cnt;
        if (cnt < bestC) { bestC = cnt; bestP = p; }  // pick LEAST-hit position
      }
      w |= 1u << bestP;
      for (int g = 0; g < 64; ++g)
        if (alive[g] && ((TB.gm[g] >> bestP) & 1u)) { alive[g] = false; ++covered; }
    }
    if (covered < bestBad) { bestBad = covered; bh = h; bw = w; }
  }
  A.hpos = bh; A.wset = bw;

  unsigned rem = 0xFFFFu & ~bw & ~(1u << bh);
  int pos[12] = {}; int np = 0;
  for (int p = 0; p < 16; ++p) if ((rem >> p) & 1u) pos[np++] = p;
  int bestLoc = -1; unsigned br = 0;
  for (int a = 0; a < 12; ++a) for (int b = a + 1; b < 12; ++b)
    for (int c = b + 1; c < 12; ++c) for (int d = c + 1; d < 12; ++d)
      for (int e = d + 1; e < 12; ++e) for (int f2 = e + 1; f2 < 12; ++f2) {
        unsigned r = (1u << pos[a]) | (1u << pos[b]) | (1u << pos[c]) |
                     (1u << pos[d]) | (1u << pos[e]) | (1u << pos[f2]);
        unsigned localset = r | (1u << bh);
        int loc = 0;
        for (int g = 0; g < 64; ++g) if ((TB.gm[g] & ~localset) == 0u) ++loc;
        if (loc > bestLoc) { bestLoc = loc; br = r; }
      }
  A.rset = br; A.lset = rem & ~br;

  int pr = 0, pl = 7, pw = 13;
  for (int p = 0; p < 16; ++p) {
    if ((A.rset >> p) & 1u)      { A.phys_of[p] = pr;  A.orig_of[pr] = p; ++pr; }
    else if (p == bh)            { A.phys_of[p] = 6;   A.orig_of[6]  = p; }
    else if ((A.lset >> p) & 1u) { A.phys_of[p] = pl;  A.orig_of[pl] = p; ++pl; }
    else                         { A.phys_of[p] = pw;  A.orig_of[pw] = p; ++pw; }
  }
  for (int g = 0; g < 64; ++g) {
    unsigned m = 0, c = 0;
    for (int p = 0; p < 16; ++p) {
      if ((TB.gm[g] >> p) & 1u) m |= 1u << A.phys_of[p];
      if ((TB.gc[g] >> p) & 1u) c |= 1u << A.phys_of[p];
    }
    A.pm[g] = m; A.pc[g] = c;
  }
  for (int w2 = 0; w2 < 16; ++w2) {
    unsigned mm = 0;
    for (int p = 0; p < 16; ++p) if ((TB.meas[w2] >> p) & 1u) mm |= 1u << A.phys_of[p];
    A.pmeas[w2] = mm;
  }
  return A;
}

constexpr Assign AS = make_assign();

constexpr bool check_assign() {
  for (int g = 0; g < 64; ++g) if ((popc16(AS.pm[g] & AS.pc[g]) & 1) != 1) return false;
  if (popc16(AS.rset) != 6 || popc16(AS.wset) != 3 || popc16(AS.lset) != 6) return false;
  return true;
}
static_assert(check_assign(), "assignment inconsistency");

// staging plan for BAD gates: stages of 8 rows, closed under r -> r^mr
struct RPlan { int stage[64]; int slot[64]; };
constexpr RPlan make_rplan(unsigned mr) {
  RPlan P{}; bool vis[64] = {};
  int g = 0, sl = 0;
  for (int r = 0; r < 64; ++r) if (!vis[r]) {
    int p = r ^ (int)mr;
    P.stage[r] = g; P.slot[r] = sl; vis[r] = true; ++sl;
    if (p != r) { P.stage[p] = g; P.slot[p] = sl; vis[p] = true; ++sl; }
    if (sl >= 8) { sl = 0; ++g; }
  }
  return P;
}
template<unsigned MR> constexpr RPlan rplan_v = make_rplan(MR);

// ---------------- small device helpers ----------------
template<int N, int I = 0, typename F>
__device__ __forceinline__ void sfor(F&& f) {
  if constexpr (I < N) {
    f(std::integral_constant<int, I>{});
    sfor<N, I + 1>(static_cast<F&&>(f));
  }
}

__device__ __forceinline__ int h2i(__half2 v) { return __builtin_bit_cast(int, v); }
__device__ __forceinline__ __half2 i2h(int v) { return __builtin_bit_cast(__half2, v); }
__device__ __forceinline__ unsigned h2u(__half2 v) { return __builtin_bit_cast(unsigned, v); }
__device__ __forceinline__ __half2 u2h(unsigned v) { return __builtin_bit_cast(__half2, v); }

__device__ __forceinline__ __half2 hswap(__half2 v) { __half2 r; r.x = v.y; r.y = v.x; return r; }

// role-0: y = s0*x + s1*sw(x) + s2*xp + s3*sw(xp); role-1 negates s1,s2
template<int T>
__device__ __forceinline__ __half2 upd(__half2 x, __half2 xp, const __half2 (&s)[4]) {
  __half2 y = __hmul2(s[0], x);
  if constexpr (T) {
    y = __hfma2(__hneg2(s[1]), hswap(x), y);
    y = __hfma2(__hneg2(s[2]), xp, y);
  } else {
    y = __hfma2(s[1], hswap(x), y);
    y = __hfma2(s[2], xp, y);
  }
  y = __hfma2(s[3], hswap(xp), y);
  return y;
}

// SU(2) for U = Ry(c) Rz(b) Ry(a):  U = [[al, -conj(be)], [be, conj(al)]]
__device__ __forceinline__ void su2_coeffs(float a, float b, float c,
                                           float& are, float& aim, float& bre, float& bim) {
  float sapc, capc, samc, camc, sb, cb;
  __sincosf((a + c) * 0.5f, &sapc, &capc);
  __sincosf((a - c) * 0.5f, &samc, &camc);
  __sincosf(b * 0.5f, &sb, &cb);
  are = cb * capc;
  aim = -sb * camc;
  bre = cb * sapc;
  bim = sb * samc;
}

__device__ __forceinline__ unsigned pkh2(float lo, float hi) {
  return h2u(__floats2half2_rn(lo, hi));
}

__device__ __forceinline__ float2 cmulf(float2 a, float vr, float vi) {
  return make_float2(a.x * vr - a.y * vi, a.x * vi + a.y * vr);
}

// ---------------- generalized gate application ----------------
// physical j = r | h<<6 | tid<<7.  R[r] = (r,h=0); ldsS[r*512+tid] = (r,h=1).
template<int G>
__device__ __forceinline__ void apply_gate(__half2 (&R)[64], unsigned tid,
                                           const unsigned* ctab, unsigned* ldsS,
                                           unsigned* xbuf) {
  constexpr unsigned m   = AS.pm[G];
  constexpr unsigned c   = AS.pc[G];
  constexpr unsigned mr  = m & 63u;
  constexpr unsigned mh  = (m >> 6) & 1u;
  constexpr unsigned mt  = (m >> 7) & 511u;
  constexpr unsigned mw  = m >> 13;
  constexpr unsigned cr  = c & 63u;
  constexpr unsigned chb = (c >> 6) & 1u;

  const unsigned f  = __popc((c >> 7) & tid) & 1u;
  const unsigned fm = f ? 0x80008000u : 0u;
  __half2 s[4];
  s[0] = u2h(ctab[G * 4 + 0]);
  s[1] = u2h(ctab[G * 4 + 1] ^ fm);
  s[2] = u2h(ctab[G * 4 + 2] ^ fm);
  s[3] = u2h(ctab[G * 4 + 3]);

  constexpr bool curLocal  = (m >> 7) == 0u;
  constexpr bool prevLocal = (G == 0) ? true : ((AS.pm[G - 1] >> 7) == 0u);
  if constexpr (!(curLocal && prevLocal)) __syncthreads();

  if constexpr (mt == 0u) {
    if constexpr (mh == 0u) {
      // ---- thread-local: reg pairs + own-slice LDS pairs ----
      constexpr int hb = topbit_pow(mr);
      sfor<32>([&](auto ii) {
        constexpr int i  = decltype(ii)::value;
        constexpr int r0 = ((i & ~(hb - 1)) << 1) | (i & (hb - 1));
        constexpr int r1 = r0 ^ (int)mr;
        constexpr int t0 = popc16(cr & (unsigned)r0) & 1;
        {
          const __half2 x0 = R[r0], x1 = R[r1];
          R[r0] = upd<t0>(x0, x1, s);
          R[r1] = upd<t0 ^ 1>(x1, x0, s);
        }
        {
          constexpr int tl = t0 ^ (int)chb;
          const __half2 x0 = u2h(ldsS[r0 * 512 + tid]);
          const __half2 x1 = u2h(ldsS[r1 * 512 + tid]);
          ldsS[r0 * 512 + tid] = h2u(upd<tl>(x0, x1, s));
          ldsS[r1 * 512 + tid] = h2u(upd<tl ^ 1>(x1, x0, s));
        }
      });
    } else {
      // ---- thread-local h gate: reg r <-> own LDS row r^mr ----
      sfor<64>([&](auto rr) {
        constexpr int r = decltype(rr)::value;
        constexpr int t = popc16(cr & (unsigned)r) & 1;
        const __half2 x = R[r];
        const __half2 y = u2h(ldsS[(r ^ (int)mr) * 512 + tid]);
        R[r] = upd<t>(x, y, s);
        ldsS[(r ^ (int)mr) * 512 + tid] = h2u(upd<t ^ 1>(y, x, s));
      });
    }
  } else if constexpr (mh == 1u) {
    // ---- cross-thread h gate: reg <-> partner-LDS (any mt incl wave);
    // single accessor per word -> no staging, no intra-gate barrier.
    const unsigned pt = tid ^ mt;
    sfor<64>([&](auto rr) {
      constexpr int r = decltype(rr)::value;
      constexpr int t = popc16(cr & (unsigned)r) & 1;
      const __half2 x = R[r];
      const __half2 y = u2h(ldsS[(r ^ (int)mr) * 512 + pt]);
      R[r] = upd<t>(x, y, s);
      ldsS[(r ^ (int)mr) * 512 + pt] = h2u(upd<t ^ 1>(y, x, s));
    });
  } else {
    // ---- mh==0, cross-thread: LDS owner-protocol + reg half ----
    const unsigned pt = tid ^ mt;
    if constexpr (mr != 0u) {
      constexpr int q = ctzu(mr);            // owner iff bit q of r == 0
      sfor<64>([&](auto rr) {
        constexpr int r = decltype(rr)::value;
        if constexpr (((r >> q) & 1) == 0) {
          constexpr int r2 = r ^ (int)mr;
          constexpr int t  = (popc16(cr & (unsigned)r) & 1) ^ (int)chb;
          const __half2 x = u2h(ldsS[r * 512 + tid]);
          const __half2 y = u2h(ldsS[r2 * 512 + pt]);
          ldsS[r * 512 + tid] = h2u(upd<t>(x, y, s));
          ldsS[r2 * 512 + pt] = h2u(upd<t ^ 1>(y, x, s));
        }
      });
    } else {
      // same row both sides: balance ownership by row bit vs tid bit
      const unsigned po = (tid >> ctzu(mt)) & 1u;
      sfor<64>([&](auto rr) {
        constexpr int r  = decltype(rr)::value;
        constexpr int r5 = (r >> 5) & 1;
        constexpr int t  = (popc16(cr & (unsigned)r) & 1) ^ (int)chb;
        if (po == (unsigned)r5) {
          const __half2 x = u2h(ldsS[r * 512 + tid]);
          const __half2 y = u2h(ldsS[r * 512 + pt]);
          ldsS[r * 512 + tid] = h2u(upd<t>(x, y, s));
          ldsS[r * 512 + pt]  = h2u(upd<t ^ 1>(y, x, s));
        }
      });
    }
    // reg half
    if constexpr (mw == 0u) {
      if constexpr (mr == 0u) {
        sfor<64>([&](auto rr) {
          constexpr int r = decltype(rr)::value;
          constexpr int t = popc16(cr & (unsigned)r) & 1;
          const __half2 xp = i2h(__shfl_xor(h2i(R[r]), (int)mt, 64));
          R[r] = upd<t>(R[r], xp, s);
        });
      } else {
        constexpr int hb = topbit_pow(mr);
        constexpr int dt = popc16(cr & mr) & 1;
        sfor<32>([&](auto ii) {
          constexpr int i  = decltype(ii)::value;
          constexpr int r0 = ((i & ~(hb - 1)) << 1) | (i & (hb - 1));
          constexpr int r1 = r0 ^ (int)mr;
          constexpr int t  = popc16(cr & (unsigned)r0) & 1;
          const __half2 x0 = R[r0], x1 = R[r1];
          const __half2 xp0 = i2h(__shfl_xor(h2i(x1), (int)mt, 64));
          const __half2 xp1 = i2h(__shfl_xor(h2i(x0), (int)mt, 64));
          R[r0] = upd<t>(x0, xp0, s);
          R[r1] = upd<t ^ dt>(x1, xp1, s);
        });
      }
    } else {
      // BAD gate: wave-crossing regs; staged exchange, 8 rows/stage
      sfor<8>([&](auto gi) {
        constexpr int gidx = decltype(gi)::value;
        sfor<64>([&](auto rr) {
          constexpr int r = decltype(rr)::value;
          if constexpr (rplan_v<mr>.stage[r] == gidx)
            xbuf[rplan_v<mr>.slot[r] * 512 + tid] = h2u(R[r]);
        });
        __syncthreads();
        sfor<64>([&](auto rr) {
          constexpr int r = decltype(rr)::value;
          if constexpr (rplan_v<mr>.stage[r] == gidx) {
            constexpr int t = popc16(cr & (unsigned)r) & 1;
            const __half2 xp = u2h(xbuf[rplan_v<mr>.slot[r ^ (int)mr] * 512 + pt]);
            R[r] = upd<t>(R[r], xp, s);
          }
        });
        __syncthreads();
      });
    }
  }
}

// ---------------- main kernel ----------------
__global__ __launch_bounds__(512, 2)
void qcir_kernel(const float* __restrict__ inputs, const float* __restrict__ weight,
                 float* __restrict__ out) {
  __shared__ unsigned ldsS[64 * 512];    // 128 KB: h=1 state half
  __shared__ unsigned xbuf[8 * 512];     // 16 KB: staging for BAD gates
  __shared__ unsigned ctab[64 * 4];      // per-gate packed coeffs
  __shared__ float4   itab[16];          // per-wire (al,be) after enc+L1
  __shared__ float    red[8 * 16];       // reduction scratch

  const unsigned tid = threadIdx.x;
  const unsigned b   = blockIdx.x;

  // ---- coefficient tables ----
  if (tid < 64) {
    const int g  = (int)tid;
    const int k  = g >> 4;
    const int bb = g & 15;
    const int w  = 15 - bb;
    const int base = 48 * (k + 1) + 3 * w;
    float are, aim, bre, bim;
    su2_coeffs(weight[base], weight[base + 1], weight[base + 2], are, aim, bre, bim);
    ctab[g * 4 + 0] = pkh2(are, are);
    ctab[g * 4 + 1] = pkh2(-aim, aim);
    ctab[g * 4 + 2] = pkh2(-bre, -bre);
    ctab[g * 4 + 3] = pkh2(-bim, bim);
  } else if (tid < 80) {
    const int w = (int)tid - 64;
    const float a = weight[3 * w] + inputs[b * 16 + w];
    float are, aim, bre, bim;
    su2_coeffs(a, weight[3 * w + 1], weight[3 * w + 2], are, aim, bre, bim);
    itab[w] = make_float4(are, aim, bre, bim);
  }
  __syncthreads();

  // ---- init: product state after encoding + layer 1 (A1 = I) ----
  __half2 R[64];
  float2 P0 = make_float2(1.f, 0.f);
#pragma unroll
  for (int pp = 7; pp < 16; ++pp) {
    const int bit = (int)(tid >> (pp - 7)) & 1;
    const float4 tt = itab[15 - AS.orig_of[pp]];
    P0 = cmulf(P0, bit ? tt.z : tt.x, bit ? tt.w : tt.y);
  }
  const float4 th = itab[15 - AS.orig_of[6]];
  const float2 Ph0 = cmulf(P0, th.x, th.y);
  const float2 Ph1 = cmulf(P0, th.z, th.w);
  sfor<64>([&](auto rr) {
    constexpr int r = decltype(rr)::value;
    float2 v0 = Ph0, v1 = Ph1;
    sfor<6>([&](auto qq) {
      constexpr int q   = decltype(qq)::value;
      constexpr int bit = (r >> q) & 1;
      const float4 tq = itab[15 - AS.orig_of[q]];
      if constexpr (bit) { v0 = cmulf(v0, tq.z, tq.w); v1 = cmulf(v1, tq.z, tq.w); }
      else               { v0 = cmulf(v0, tq.x, tq.y); v1 = cmulf(v1, tq.x, tq.y); }
    });
    R[r] = __floats2half2_rn(v0.x, v0.y);
    ldsS[r * 512 + tid] = h2u(__floats2half2_rn(v1.x, v1.y));
  });

  // ---- layers 2..5: 64 generalized gates ----
  sfor<64>([&](auto gg) { apply_gate<decltype(gg)::value>(R, tid, ctab, ldsS, xbuf); });

  // ---- measurement: <Z_w> via signed probability sums ----
  __syncthreads();
  float acc[16];
  sfor<16>([&](auto ww) { acc[decltype(ww)::value] = 0.f; });
  sfor<64>([&](auto rr) {          // register half (h=0)
    constexpr int r = decltype(rr)::value;
    const float re = __low2float(R[r]);
    const float im = __high2float(R[r]);
    const float p = re * re + im * im;
    sfor<16>([&](auto ww) {
      constexpr int w = decltype(ww)::value;
      constexpr int t = popc16(AS.pmeas[w] & 63u & (unsigned)r) & 1;
      if constexpr (t) acc[w] -= p; else acc[w] += p;
    });
  });
  sfor<64>([&](auto rr) {          // LDS half (h=1)
    constexpr int r = decltype(rr)::value;
    const __half2 v = u2h(ldsS[r * 512 + tid]);
    const float re = __low2float(v);
    const float im = __high2float(v);
    const float p = re * re + im * im;
    sfor<16>([&](auto ww) {
      constexpr int w = decltype(ww)::value;
      constexpr int t = (popc16(AS.pmeas[w] & 63u & (unsigned)r) & 1) ^
                        (int)((AS.pmeas[w] >> 6) & 1u);
      if constexpr (t) acc[w] -= p; else acc[w] += p;
    });
  });
  sfor<16>([&](auto ww) {
    constexpr int w = decltype(ww)::value;
    const unsigned fw = __popc((AS.pmeas[w] >> 7) & tid) & 1u;
    float z = fw ? -acc[w] : acc[w];
#pragma unroll
    for (int d = 1; d < 64; d <<= 1) z += __shfl_xor(z, d, 64);
    if ((tid & 63u) == 0u) red[(tid >> 6) * 16 + w] = z;
  });
  __syncthreads();
  if (tid < 16) {
    float sum = 0.f;
#pragma unroll
    for (int v = 0; v < 8; ++v) sum += red[v * 16 + tid];
    out[b * 16 + tid] = 4.f * sum;
  }
}

// ---------------- launcher ----------------
extern "C" void kernel_launch(void* const* d_in, const int* in_sizes, int n_in,
                              void* d_out, int out_size, void* d_ws, size_t ws_size,
                              hipStream_t stream) {
  const float* inputs = (const float*)d_in[0];   // (B, 16) f32
  const float* weight = (const float*)d_in[1];   // (240,)  f32
  float* out = (float*)d_out;                    // (B, 16) f32
  const int B = in_sizes[0] / 16;
  qcir_kernel<<<B, 512, 0, stream>>>(inputs, weight, out);
}

// Round 10
// 415.324 us; speedup vs baseline: 2.2601x; 2.2601x over previous
//
#include <hip/hip_runtime.h>
#include <hip/hip_fp16.h>
#include <utility>
#include <type_traits>

// =====================================================================
// 16-qubit, batch-256 statevector simulator.  R10 = R9 + sched discipline.
//
//  * one workgroup (512 threads) per batch element; 128 amps/thread,
//    SPLIT: 64 in registers (h=0) + 64 in a 128 KB LDS array (h=1).
//  * R9 proved 512-thr kernels get a 128-VGPR budget (VGPR_Count=128)
//    but still spilled: the fully-unrolled gate bodies let the scheduler
//    hoist ds_reads until pressure exceeded 128.  R10 chunks every LDS
//    RMW loop with __builtin_amdgcn_sched_barrier(0) (<=8-16 loads in
//    flight) and fences between gates -> worst-case pressure ~95 < 128.
//  * CNOT rings virtualized into GF(2) storage maps; gates are pair
//    updates j <-> j^m with role parity(c&j) (R8/R9-validated).
//  * physical j = [r:6][h:1][lane:6][wave:3].  Gate taxonomy:
//      - m thread-local        -> reg pairs + own-slice LDS pairs
//      - m has h               -> reg <-> partner-LDS direct (any mt)
//      - m lane-only, no h     -> shfl (regs) + LDS owner-protocol
//      - m wave-crossing, no h -> BAD: staged exchange (regs) + owner
//    constexpr greedy picks h + 3 wave bits to minimize BAD gates.
// =====================================================================

// ---------------- compile-time GF(2) matrices ----------------
struct M16 { unsigned r[16]; };

constexpr M16 ident() { M16 m{}; for (int i = 0; i < 16; ++i) m.r[i] = 1u << i; return m; }

constexpr M16 ringm(int s) {
  M16 m = ident();
  for (int i = 15; i >= 0; --i) {
    int pc = 15 - i;
    int pt = 15 - ((i + s) & 15);
    m.r[pt] ^= m.r[pc];
  }
  return m;
}

constexpr M16 mmul(M16 A, M16 B) {
  M16 C{};
  for (int p = 0; p < 16; ++p) {
    unsigned v = 0;
    for (int q = 0; q < 16; ++q) if ((A.r[p] >> q) & 1u) v ^= B.r[q];
    C.r[p] = v;
  }
  return C;
}

constexpr M16 minv(M16 A) {
  M16 I = ident();
  for (int col = 0; col < 16; ++col) {
    int piv = -1;
    for (int row = col; row < 16; ++row) if ((A.r[row] >> col) & 1u) { piv = row; break; }
    unsigned t = A.r[piv]; A.r[piv] = A.r[col]; A.r[col] = t;
    t = I.r[piv]; I.r[piv] = I.r[col]; I.r[col] = t;
    for (int row = 0; row < 16; ++row)
      if (row != col && ((A.r[row] >> col) & 1u)) { A.r[row] ^= A.r[col]; I.r[row] ^= I.r[col]; }
  }
  return I;
}

constexpr bool meq(M16 a, M16 b) { for (int i = 0; i < 16; ++i) if (a.r[i] != b.r[i]) return false; return true; }
constexpr unsigned colmask(M16 P, int b) { unsigned m = 0; for (int p = 0; p < 16; ++p) m |= ((P.r[p] >> b) & 1u) << p; return m; }
constexpr int popc16(unsigned x) { int c = 0; for (int i = 0; i < 16; ++i) c += (x >> i) & 1; return c; }
constexpr int topbit_pow(unsigned x) { int b = 0; for (int i = 0; i < 16; ++i) if ((x >> i) & 1) b = i; return 1 << b; }
constexpr int ctzu(unsigned x) { for (int i = 0; i < 32; ++i) if ((x >> i) & 1) return i; return 32; }

struct Tables { unsigned gm[64]; unsigned gc[64]; unsigned meas[16]; };

constexpr Tables make_tables() {
  Tables T{};
  M16 R1 = ringm(1), R2 = ringm(2);
  M16 P0 = R1;
  M16 P1 = mmul(R1, R1);
  M16 P2 = mmul(P1, R2);
  M16 P3 = mmul(P2, R2);
  M16 P[4] = { P0, P1, P2, P3 };
  for (int k = 0; k < 4; ++k) {
    M16 A = minv(P[k]);
    for (int b = 0; b < 16; ++b) {
      T.gm[k * 16 + b] = colmask(P[k], b);
      T.gc[k * 16 + b] = A.r[b];
    }
  }
  M16 A5 = minv(P[3]);
  for (int w = 0; w < 16; ++w) T.meas[w] = A5.r[15 - w];
  return T;
}

constexpr Tables TB = make_tables();

constexpr bool check_tables() {
  for (int g = 0; g < 64; ++g) if ((popc16(TB.gm[g] & TB.gc[g]) & 1) != 1) return false;
  if (!meq(mmul(ringm(1), minv(ringm(1))), ident())) return false;
  if (!meq(mmul(ringm(2), minv(ringm(2))), ident())) return false;
  return true;
}
static_assert(check_tables(), "GF(2) table inconsistency");
static_assert(sizeof(__half2) == 4, "half2 size");

// ---------------- bit-role assignment (constexpr greedy) ----------------
struct Assign {
  int hpos; unsigned wset, rset, lset;
  int phys_of[16];
  int orig_of[16];
  unsigned pm[64], pc[64], pmeas[16];
};

constexpr Assign make_assign() {
  Assign A{};
  int bestBad = 1000, bh = -1; unsigned bw = 0;
  for (int h = 0; h < 16; ++h) {
    bool alive[64];
    for (int g = 0; g < 64; ++g) alive[g] = ((TB.gm[g] >> h) & 1u) == 0u;
    unsigned w = 0;
    int covered = 0;
    for (int pick = 0; pick < 3; ++pick) {
      int bestP = -1, bestC = 1000000;
      for (int p = 0; p < 16; ++p) {
        if (p == h || ((w >> p) & 1u)) continue;
        int cnt = 0;
        for (int g = 0; g < 64; ++g)
          if (alive[g] && ((TB.gm[g] >> p) & 1u)) ++cnt;
        if (cnt < bestC) { bestC = cnt; bestP = p; }
      }
      w |= 1u << bestP;
      for (int g = 0; g < 64; ++g)
        if (alive[g] && ((TB.gm[g] >> bestP) & 1u)) { alive[g] = false; ++covered; }
    }
    if (covered < bestBad) { bestBad = covered; bh = h; bw = w; }
  }
  A.hpos = bh; A.wset = bw;

  unsigned rem = 0xFFFFu & ~bw & ~(1u << bh);
  int pos[12] = {}; int np = 0;
  for (int p = 0; p < 16; ++p) if ((rem >> p) & 1u) pos[np++] = p;
  int bestLoc = -1; unsigned br = 0;
  for (int a = 0; a < 12; ++a) for (int b = a + 1; b < 12; ++b)
    for (int c = b + 1; c < 12; ++c) for (int d = c + 1; d < 12; ++d)
      for (int e = d + 1; e < 12; ++e) for (int f2 = e + 1; f2 < 12; ++f2) {
        unsigned r = (1u << pos[a]) | (1u << pos[b]) | (1u << pos[c]) |
                     (1u << pos[d]) | (1u << pos[e]) | (1u << pos[f2]);
        unsigned localset = r | (1u << bh);
        int loc = 0;
        for (int g = 0; g < 64; ++g) if ((TB.gm[g] & ~localset) == 0u) ++loc;
        if (loc > bestLoc) { bestLoc = loc; br = r; }
      }
  A.rset = br; A.lset = rem & ~br;

  int pr = 0, pl = 7, pw = 13;
  for (int p = 0; p < 16; ++p) {
    if ((A.rset >> p) & 1u)      { A.phys_of[p] = pr;  A.orig_of[pr] = p; ++pr; }
    else if (p == bh)            { A.phys_of[p] = 6;   A.orig_of[6]  = p; }
    else if ((A.lset >> p) & 1u) { A.phys_of[p] = pl;  A.orig_of[pl] = p; ++pl; }
    else                         { A.phys_of[p] = pw;  A.orig_of[pw] = p; ++pw; }
  }
  for (int g = 0; g < 64; ++g) {
    unsigned m = 0, c = 0;
    for (int p = 0; p < 16; ++p) {
      if ((TB.gm[g] >> p) & 1u) m |= 1u << A.phys_of[p];
      if ((TB.gc[g] >> p) & 1u) c |= 1u << A.phys_of[p];
    }
    A.pm[g] = m; A.pc[g] = c;
  }
  for (int w2 = 0; w2 < 16; ++w2) {
    unsigned mm = 0;
    for (int p = 0; p < 16; ++p) if ((TB.meas[w2] >> p) & 1u) mm |= 1u << A.phys_of[p];
    A.pmeas[w2] = mm;
  }
  return A;
}

constexpr Assign AS = make_assign();

constexpr bool check_assign() {
  for (int g = 0; g < 64; ++g) if ((popc16(AS.pm[g] & AS.pc[g]) & 1) != 1) return false;
  if (popc16(AS.rset) != 6 || popc16(AS.wset) != 3 || popc16(AS.lset) != 6) return false;
  return true;
}
static_assert(check_assign(), "assignment inconsistency");

// staging plan for BAD gates: stages of 8 rows, closed under r -> r^mr
struct RPlan { int stage[64]; int slot[64]; };
constexpr RPlan make_rplan(unsigned mr) {
  RPlan P{}; bool vis[64] = {};
  int g = 0, sl = 0;
  for (int r = 0; r < 64; ++r) if (!vis[r]) {
    int p = r ^ (int)mr;
    P.stage[r] = g; P.slot[r] = sl; vis[r] = true; ++sl;
    if (p != r) { P.stage[p] = g; P.slot[p] = sl; vis[p] = true; ++sl; }
    if (sl >= 8) { sl = 0; ++g; }
  }
  return P;
}
template<unsigned MR> constexpr RPlan rplan_v = make_rplan(MR);

// ---------------- small device helpers ----------------
template<int N, int I = 0, typename F>
__device__ __forceinline__ void sfor(F&& f) {
  if constexpr (I < N) {
    f(std::integral_constant<int, I>{});
    sfor<N, I + 1>(static_cast<F&&>(f));
  }
}

__device__ __forceinline__ void sbar() { __builtin_amdgcn_sched_barrier(0); }

__device__ __forceinline__ int h2i(__half2 v) { return __builtin_bit_cast(int, v); }
__device__ __forceinline__ __half2 i2h(int v) { return __builtin_bit_cast(__half2, v); }
__device__ __forceinline__ unsigned h2u(__half2 v) { return __builtin_bit_cast(unsigned, v); }
__device__ __forceinline__ __half2 u2h(unsigned v) { return __builtin_bit_cast(__half2, v); }

__device__ __forceinline__ __half2 hswap(__half2 v) { __half2 r; r.x = v.y; r.y = v.x; return r; }

// role-0: y = s0*x + s1*sw(x) + s2*xp + s3*sw(xp); role-1 negates s1,s2
template<int T>
__device__ __forceinline__ __half2 upd(__half2 x, __half2 xp, const __half2 (&s)[4]) {
  __half2 y = __hmul2(s[0], x);
  if constexpr (T) {
    y = __hfma2(__hneg2(s[1]), hswap(x), y);
    y = __hfma2(__hneg2(s[2]), xp, y);
  } else {
    y = __hfma2(s[1], hswap(x), y);
    y = __hfma2(s[2], xp, y);
  }
  y = __hfma2(s[3], hswap(xp), y);
  return y;
}

// SU(2) for U = Ry(c) Rz(b) Ry(a):  U = [[al, -conj(be)], [be, conj(al)]]
__device__ __forceinline__ void su2_coeffs(float a, float b, float c,
                                           float& are, float& aim, float& bre, float& bim) {
  float sapc, capc, samc, camc, sb, cb;
  __sincosf((a + c) * 0.5f, &sapc, &capc);
  __sincosf((a - c) * 0.5f, &samc, &camc);
  __sincosf(b * 0.5f, &sb, &cb);
  are = cb * capc;
  aim = -sb * camc;
  bre = cb * sapc;
  bim = sb * samc;
}

__device__ __forceinline__ unsigned pkh2(float lo, float hi) {
  return h2u(__floats2half2_rn(lo, hi));
}

__device__ __forceinline__ float2 cmulf(float2 a, float vr, float vi) {
  return make_float2(a.x * vr - a.y * vi, a.x * vi + a.y * vr);
}

// ---------------- generalized gate application ----------------
// physical j = r | h<<6 | tid<<7.  R[r] = (r,h=0); ldsS[r*512+tid] = (r,h=1).
template<int G>
__device__ __forceinline__ void apply_gate(__half2 (&R)[64], unsigned tid,
                                           const unsigned* ctab, unsigned* ldsS,
                                           unsigned* xbuf) {
  constexpr unsigned m   = AS.pm[G];
  constexpr unsigned c   = AS.pc[G];
  constexpr unsigned mr  = m & 63u;
  constexpr unsigned mh  = (m >> 6) & 1u;
  constexpr unsigned mt  = (m >> 7) & 511u;
  constexpr unsigned mw  = m >> 13;
  constexpr unsigned cr  = c & 63u;
  constexpr unsigned chb = (c >> 6) & 1u;

  const unsigned f  = __popc((c >> 7) & tid) & 1u;
  const unsigned fm = f ? 0x80008000u : 0u;
  __half2 s[4];
  s[0] = u2h(ctab[G * 4 + 0]);
  s[1] = u2h(ctab[G * 4 + 1] ^ fm);
  s[2] = u2h(ctab[G * 4 + 2] ^ fm);
  s[3] = u2h(ctab[G * 4 + 3]);

  constexpr bool curLocal  = (m >> 7) == 0u;
  constexpr bool prevLocal = (G == 0) ? true : ((AS.pm[G - 1] >> 7) == 0u);
  if constexpr (!(curLocal && prevLocal)) __syncthreads();

  if constexpr (mt == 0u) {
    if constexpr (mh == 0u) {
      // ---- thread-local: reg pairs, then own-slice LDS pairs (chunked)
      constexpr int hb = topbit_pow(mr);
      sfor<32>([&](auto ii) {
        constexpr int i  = decltype(ii)::value;
        constexpr int r0 = ((i & ~(hb - 1)) << 1) | (i & (hb - 1));
        constexpr int r1 = r0 ^ (int)mr;
        constexpr int t0 = popc16(cr & (unsigned)r0) & 1;
        const __half2 x0 = R[r0], x1 = R[r1];
        R[r0] = upd<t0>(x0, x1, s);
        R[r1] = upd<t0 ^ 1>(x1, x0, s);
      });
      sbar();
      sfor<32>([&](auto ii) {
        constexpr int i  = decltype(ii)::value;
        constexpr int r0 = ((i & ~(hb - 1)) << 1) | (i & (hb - 1));
        constexpr int r1 = r0 ^ (int)mr;
        constexpr int t0 = popc16(cr & (unsigned)r0) & 1;
        constexpr int tl = t0 ^ (int)chb;
        const __half2 x0 = u2h(ldsS[r0 * 512 + tid]);
        const __half2 x1 = u2h(ldsS[r1 * 512 + tid]);
        ldsS[r0 * 512 + tid] = h2u(upd<tl>(x0, x1, s));
        ldsS[r1 * 512 + tid] = h2u(upd<tl ^ 1>(x1, x0, s));
        if constexpr ((i & 3) == 3) sbar();   // cap: 8 loads in flight
      });
    } else {
      // ---- thread-local h gate: reg r <-> own LDS row r^mr (chunked)
      sfor<64>([&](auto rr) {
        constexpr int r = decltype(rr)::value;
        constexpr int t = popc16(cr & (unsigned)r) & 1;
        const __half2 x = R[r];
        const __half2 y = u2h(ldsS[(r ^ (int)mr) * 512 + tid]);
        R[r] = upd<t>(x, y, s);
        ldsS[(r ^ (int)mr) * 512 + tid] = h2u(upd<t ^ 1>(y, x, s));
        if constexpr ((r & 7) == 7) sbar();   // cap: 8 loads in flight
      });
    }
  } else if constexpr (mh == 1u) {
    // ---- cross-thread h gate: reg <-> partner-LDS (any mt incl wave);
    // single accessor per word -> no staging, no intra-gate barrier.
    const unsigned pt = tid ^ mt;
    sfor<64>([&](auto rr) {
      constexpr int r = decltype(rr)::value;
      constexpr int t = popc16(cr & (unsigned)r) & 1;
      const __half2 x = R[r];
      const __half2 y = u2h(ldsS[(r ^ (int)mr) * 512 + pt]);
      R[r] = upd<t>(x, y, s);
      ldsS[(r ^ (int)mr) * 512 + pt] = h2u(upd<t ^ 1>(y, x, s));
      if constexpr ((r & 7) == 7) sbar();     // cap: 8 loads in flight
    });
  } else {
    // ---- mh==0, cross-thread: LDS owner-protocol + reg half ----
    const unsigned pt = tid ^ mt;
    if constexpr (mr != 0u) {
      constexpr int q = ctzu(mr);            // owner iff bit q of r == 0
      sfor<64>([&](auto rr) {
        constexpr int r = decltype(rr)::value;
        if constexpr (((r >> q) & 1) == 0) {
          constexpr int r2 = r ^ (int)mr;
          constexpr int t  = (popc16(cr & (unsigned)r) & 1) ^ (int)chb;
          const __half2 x = u2h(ldsS[r * 512 + tid]);
          const __half2 y = u2h(ldsS[r2 * 512 + pt]);
          ldsS[r * 512 + tid] = h2u(upd<t>(x, y, s));
          ldsS[r2 * 512 + pt] = h2u(upd<t ^ 1>(y, x, s));
        }
        if constexpr ((r & 7) == 7) sbar();   // cap: ~8 loads in flight
      });
    } else {
      // same row both sides: balance ownership by row bit vs tid bit
      const unsigned po = (tid >> ctzu(mt)) & 1u;
      sfor<64>([&](auto rr) {
        constexpr int r  = decltype(rr)::value;
        constexpr int r5 = (r >> 5) & 1;
        constexpr int t  = (popc16(cr & (unsigned)r) & 1) ^ (int)chb;
        if (po == (unsigned)r5) {
          const __half2 x = u2h(ldsS[r * 512 + tid]);
          const __half2 y = u2h(ldsS[r * 512 + pt]);
          ldsS[r * 512 + tid] = h2u(upd<t>(x, y, s));
          ldsS[r * 512 + pt]  = h2u(upd<t ^ 1>(y, x, s));
        }
        if constexpr ((r & 7) == 7) sbar();   // cap loads in flight
      });
    }
    sbar();
    // reg half
    if constexpr (mw == 0u) {
      if constexpr (mr == 0u) {
        sfor<64>([&](auto rr) {
          constexpr int r = decltype(rr)::value;
          constexpr int t = popc16(cr & (unsigned)r) & 1;
          const __half2 xp = i2h(__shfl_xor(h2i(R[r]), (int)mt, 64));
          R[r] = upd<t>(R[r], xp, s);
          if constexpr ((r & 15) == 15) sbar();
        });
      } else {
        constexpr int hb = topbit_pow(mr);
        constexpr int dt = popc16(cr & mr) & 1;
        sfor<32>([&](auto ii) {
          constexpr int i  = decltype(ii)::value;
          constexpr int r0 = ((i & ~(hb - 1)) << 1) | (i & (hb - 1));
          constexpr int r1 = r0 ^ (int)mr;
          constexpr int t  = popc16(cr & (unsigned)r0) & 1;
          const __half2 x0 = R[r0], x1 = R[r1];
          const __half2 xp0 = i2h(__shfl_xor(h2i(x1), (int)mt, 64));
          const __half2 xp1 = i2h(__shfl_xor(h2i(x0), (int)mt, 64));
          R[r0] = upd<t>(x0, xp0, s);
          R[r1] = upd<t ^ dt>(x1, xp1, s);
          if constexpr ((i & 7) == 7) sbar();
        });
      }
    } else {
      // BAD gate: wave-crossing regs; staged exchange, 8 rows/stage
      sfor<8>([&](auto gi) {
        constexpr int gidx = decltype(gi)::value;
        sfor<64>([&](auto rr) {
          constexpr int r = decltype(rr)::value;
          if constexpr (rplan_v<mr>.stage[r] == gidx)
            xbuf[rplan_v<mr>.slot[r] * 512 + tid] = h2u(R[r]);
        });
        __syncthreads();
        sfor<64>([&](auto rr) {
          constexpr int r = decltype(rr)::value;
          if constexpr (rplan_v<mr>.stage[r] == gidx) {
            constexpr int t = popc16(cr & (unsigned)r) & 1;
            const __half2 xp = u2h(xbuf[rplan_v<mr>.slot[r ^ (int)mr] * 512 + pt]);
            R[r] = upd<t>(R[r], xp, s);
          }
        });
        __syncthreads();
      });
    }
  }
  sbar();   // fence: no hoisting of next gate's loads into this gate
}

// ---------------- main kernel ----------------
__global__ __launch_bounds__(512, 2)
void qcir_kernel(const float* __restrict__ inputs, const float* __restrict__ weight,
                 float* __restrict__ out) {
  __shared__ unsigned ldsS[64 * 512];    // 128 KB: h=1 state half
  __shared__ unsigned xbuf[8 * 512];     // 16 KB: staging for BAD gates
  __shared__ unsigned ctab[64 * 4];      // per-gate packed coeffs
  __shared__ float4   itab[16];          // per-wire (al,be) after enc+L1
  __shared__ float    red[8 * 16];       // reduction scratch

  const unsigned tid = threadIdx.x;
  const unsigned b   = blockIdx.x;

  // ---- coefficient tables ----
  if (tid < 64) {
    const int g  = (int)tid;
    const int k  = g >> 4;
    const int bb = g & 15;
    const int w  = 15 - bb;
    const int base = 48 * (k + 1) + 3 * w;
    float are, aim, bre, bim;
    su2_coeffs(weight[base], weight[base + 1], weight[base + 2], are, aim, bre, bim);
    ctab[g * 4 + 0] = pkh2(are, are);
    ctab[g * 4 + 1] = pkh2(-aim, aim);
    ctab[g * 4 + 2] = pkh2(-bre, -bre);
    ctab[g * 4 + 3] = pkh2(-bim, bim);
  } else if (tid < 80) {
    const int w = (int)tid - 64;
    const float a = weight[3 * w] + inputs[b * 16 + w];
    float are, aim, bre, bim;
    su2_coeffs(a, weight[3 * w + 1], weight[3 * w + 2], are, aim, bre, bim);
    itab[w] = make_float4(are, aim, bre, bim);
  }
  __syncthreads();

  // ---- init: product state after encoding + layer 1 (A1 = I) ----
  __half2 R[64];
  float2 P0 = make_float2(1.f, 0.f);
#pragma unroll
  for (int pp = 7; pp < 16; ++pp) {
    const int bit = (int)(tid >> (pp - 7)) & 1;
    const float4 tt = itab[15 - AS.orig_of[pp]];
    P0 = cmulf(P0, bit ? tt.z : tt.x, bit ? tt.w : tt.y);
  }
  const float4 th = itab[15 - AS.orig_of[6]];
  const float2 Ph0 = cmulf(P0, th.x, th.y);
  const float2 Ph1 = cmulf(P0, th.z, th.w);
  sfor<64>([&](auto rr) {
    constexpr int r = decltype(rr)::value;
    float2 v0 = Ph0, v1 = Ph1;
    sfor<6>([&](auto qq) {
      constexpr int q   = decltype(qq)::value;
      constexpr int bit = (r >> q) & 1;
      const float4 tq = itab[15 - AS.orig_of[q]];
      if constexpr (bit) { v0 = cmulf(v0, tq.z, tq.w); v1 = cmulf(v1, tq.z, tq.w); }
      else               { v0 = cmulf(v0, tq.x, tq.y); v1 = cmulf(v1, tq.x, tq.y); }
    });
    R[r] = __floats2half2_rn(v0.x, v0.y);
    ldsS[r * 512 + tid] = h2u(__floats2half2_rn(v1.x, v1.y));
    if constexpr ((r & 7) == 7) sbar();
  });

  // ---- layers 2..5: 64 generalized gates ----
  sfor<64>([&](auto gg) { apply_gate<decltype(gg)::value>(R, tid, ctab, ldsS, xbuf); });

  // ---- measurement: <Z_w> via signed probability sums ----
  __syncthreads();
  float acc[16];
  sfor<16>([&](auto ww) { acc[decltype(ww)::value] = 0.f; });
  sfor<64>([&](auto rr) {          // register half (h=0)
    constexpr int r = decltype(rr)::value;
    const float re = __low2float(R[r]);
    const float im = __high2float(R[r]);
    const float p = re * re + im * im;
    sfor<16>([&](auto ww) {
      constexpr int w = decltype(ww)::value;
      constexpr int t = popc16(AS.pmeas[w] & 63u & (unsigned)r) & 1;
      if constexpr (t) acc[w] -= p; else acc[w] += p;
    });
  });
  sbar();
  sfor<64>([&](auto rr) {          // LDS half (h=1)
    constexpr int r = decltype(rr)::value;
    const __half2 v = u2h(ldsS[r * 512 + tid]);
    const float re = __low2float(v);
    const float im = __high2float(v);
    const float p = re * re + im * im;
    sfor<16>([&](auto ww) {
      constexpr int w = decltype(ww)::value;
      constexpr int t = (popc16(AS.pmeas[w] & 63u & (unsigned)r) & 1) ^
                        (int)((AS.pmeas[w] >> 6) & 1u);
      if constexpr (t) acc[w] -= p; else acc[w] += p;
    });
    if constexpr ((r & 7) == 7) sbar();
  });
  sfor<16>([&](auto ww) {
    constexpr int w = decltype(ww)::value;
    const unsigned fw = __popc((AS.pmeas[w] >> 7) & tid) & 1u;
    float z = fw ? -acc[w] : acc[w];
#pragma unroll
    for (int d = 1; d < 64; d <<= 1) z += __shfl_xor(z, d, 64);
    if ((tid & 63u) == 0u) red[(tid >> 6) * 16 + w] = z;
  });
  __syncthreads();
  if (tid < 16) {
    float sum = 0.f;
#pragma unroll
    for (int v = 0; v < 8; ++v) sum += red[v * 16 + tid];
    out[b * 16 + tid] = 4.f * sum;
  }
}

// ---------------- launcher ----------------
extern "C" void kernel_launch(void* const* d_in, const int* in_sizes, int n_in,
                              void* d_out, int out_size, void* d_ws, size_t ws_size,
                              hipStream_t stream) {
  const float* inputs = (const float*)d_in[0];   // (B, 16) f32
  const float* weight = (const float*)d_in[1];   // (240,)  f32
  float* out = (float*)d_out;                    // (B, 16) f32
  const int B = in_sizes[0] / 16;
  qcir_kernel<<<B, 512, 0, stream>>>(inputs, weight, out);
}